// Round 4
// baseline (10.689 us; speedup 1.0000x reference)
//
#include <hip/hip_runtime.h>

// Output row (b,i): [ exp(-((xi4-xj4)^2+(xi5-xj5)^2)) for j=0..511 | x[b,i,10:20] | 30 zeros ]
// = 552 floats. x shape (8, 512, 20) fp32. Row stride 2208 B.
// Grid: 512 blocks x 256 threads, 8 rows/block (64 blocks/batch).
// Metric coords (cols 4,5) staged to LDS once per block -> compute reads are LDS,
// killing the 64-lines-per-wave-instruction global scatter of R3.

#define GS    512
#define TWO_P 20
#define P     10
#define ROWW  (GS + P + 30)   // 552
#define TPB   256
#define RPB   8               // rows per block

__global__ __launch_bounds__(TPB) void gbuilder_kernel(const float* __restrict__ x,
                                                       float* __restrict__ out) {
    const int row0 = blockIdx.x * RPB;        // first global row (b*512+i)
    const int b    = row0 >> 9;
    const int t    = threadIdx.x;

    const float* xb = x + (size_t)b * GS * TWO_P;

    __shared__ float x4s[GS];
    __shared__ float x5s[GS];

    // Stage metric coords: 2 strided float2 loads per thread (once per block).
    #pragma unroll
    for (int jj = t; jj < GS; jj += TPB) {
        const float2 c = *reinterpret_cast<const float2*>(xb + jj * TWO_P + 4);
        x4s[jj] = c.x;
        x5s[jj] = c.y;
    }
    __syncthreads();

    const int r    = t >> 5;                  // 0..7: row within block
    const int iloc = (row0 & (GS - 1)) + r;   // row index within batch
    const float xi4 = x4s[iloc];              // LDS broadcast
    const float xi5 = x5s[iloc];

    float* orow = out + (size_t)(row0 + r) * ROWW;
    const int jb = (t & 31) * 4;              // lane's base j within each 128-chunk

    #pragma unroll
    for (int q = 0; q < 4; ++q) {
        const float4 a4 = *reinterpret_cast<const float4*>(&x4s[jb + 128 * q]);
        const float4 a5 = *reinterpret_cast<const float4*>(&x5s[jb + 128 * q]);
        float4 v;
        #pragma unroll
        for (int k = 0; k < 4; ++k) {
            const float d4 = xi4 - (&a4.x)[k];
            const float d5 = xi5 - (&a5.x)[k];
            (&v.x)[k] = __expf(-(d4 * d4 + d5 * d5));
        }
        *reinterpret_cast<float4*>(orow + jb + 128 * q) = v;
    }

    // Tail: per row, elements 512..551 = 10 parax + 30 zeros = 10 float4 stores.
    if (t < 80) {
        const int rr = t / 10;
        const int s  = t % 10;
        const int ii = (row0 & (GS - 1)) + rr;
        const float* xrow = xb + ii * TWO_P;
        float4 tail = make_float4(0.f, 0.f, 0.f, 0.f);
        #pragma unroll
        for (int q = 0; q < 4; ++q) {
            const int m = 4 * s + q;
            if (m < P) (&tail.x)[q] = xrow[P + m];
        }
        *reinterpret_cast<float4*>(out + (size_t)(row0 + rr) * ROWW + GS + 4 * s) = tail;
    }
}

extern "C" void kernel_launch(void* const* d_in, const int* in_sizes, int n_in,
                              void* d_out, int out_size, void* d_ws, size_t ws_size,
                              hipStream_t stream) {
    const float* x = (const float*)d_in[0];
    float* out = (float*)d_out;
    gbuilder_kernel<<<(8 * GS) / RPB, TPB, 0, stream>>>(x, out);
}

// Round 5
// 10.528 us; speedup vs baseline: 1.0153x; 1.0153x over previous
//
#include <hip/hip_runtime.h>

// Output row (b,i): [ exp(-((xi4-xj4)^2+(xi5-xj5)^2)) for j=0..511 | x[b,i,10:20] | 30 zeros ]
// = 552 floats. x shape (8, 512, 20) fp32. Row stride 2208 B.
// Grid: 256 blocks (1/CU) x 256 threads, 16 rows/block (32 blocks/batch).
// Thread t: row r = t>>4 (16 threads/row), covers j = (t&15)*4 + 64*q + k, q=0..7.
// Metric coords (cols 4,5) staged to LDS once per block.

#define GS    512
#define TWO_P 20
#define P     10
#define ROWW  (GS + P + 30)   // 552
#define TPB   256
#define RPB   16              // rows per block

__global__ __launch_bounds__(TPB) void gbuilder_kernel(const float* __restrict__ x,
                                                       float* __restrict__ out) {
    const int row0 = blockIdx.x * RPB;        // first global row (b*512+i)
    const int b    = row0 >> 9;
    const int t    = threadIdx.x;

    const float* xb = x + (size_t)b * GS * TWO_P;

    __shared__ float x4s[GS];
    __shared__ float x5s[GS];

    #pragma unroll
    for (int jj = t; jj < GS; jj += TPB) {
        const float2 c = *reinterpret_cast<const float2*>(xb + jj * TWO_P + 4);
        x4s[jj] = c.x;
        x5s[jj] = c.y;
    }
    __syncthreads();

    const int r    = t >> 4;                  // 0..15: row within block
    const int iloc = (row0 & (GS - 1)) + r;   // row index within batch
    const float xi4 = x4s[iloc];
    const float xi5 = x5s[iloc];

    float* orow = out + (size_t)(row0 + r) * ROWW;
    const int jb = (t & 15) * 4;              // lane's base j within each 64-chunk

    #pragma unroll
    for (int q = 0; q < 8; ++q) {
        const float4 a4 = *reinterpret_cast<const float4*>(&x4s[jb + 64 * q]);
        const float4 a5 = *reinterpret_cast<const float4*>(&x5s[jb + 64 * q]);
        float4 v;
        #pragma unroll
        for (int k = 0; k < 4; ++k) {
            const float d4 = xi4 - (&a4.x)[k];
            const float d5 = xi5 - (&a5.x)[k];
            (&v.x)[k] = __expf(-(d4 * d4 + d5 * d5));
        }
        *reinterpret_cast<float4*>(orow + jb + 64 * q) = v;
    }

    // Tail: per row, elements 512..551 = 10 parax + 30 zeros = 10 float4 stores.
    // 16 rows x 10 slots = 160 threads.
    if (t < 160) {
        const int rr = t / 10;
        const int s  = t % 10;
        const int ii = (row0 & (GS - 1)) + rr;
        const float* xrow = xb + ii * TWO_P;
        float4 tail = make_float4(0.f, 0.f, 0.f, 0.f);
        #pragma unroll
        for (int q = 0; q < 4; ++q) {
            const int m = 4 * s + q;
            if (m < P) (&tail.x)[q] = xrow[P + m];
        }
        *reinterpret_cast<float4*>(out + (size_t)(row0 + rr) * ROWW + GS + 4 * s) = tail;
    }
}

extern "C" void kernel_launch(void* const* d_in, const int* in_sizes, int n_in,
                              void* d_out, int out_size, void* d_ws, size_t ws_size,
                              hipStream_t stream) {
    const float* x = (const float*)d_in[0];
    float* out = (float*)d_out;
    gbuilder_kernel<<<(8 * GS) / RPB, TPB, 0, stream>>>(x, out);
}